// Round 7
// baseline (7302.882 us; speedup 1.0000x reference)
//
#include <hip/hip_runtime.h>
#include <hip/hip_fp16.h>

typedef unsigned int u32;

#define TSTEPS 2048
#define HID    1024
#define NDEPTH 5
#define GSTAGE 51
#define NBLOCKS (NDEPTH * GSTAGE)   // 255 blocks, 1 per CU
#define HCAN   0x7c00u              // fp16 +inf: unreachable by activations
#define DCAN   0x7c007c00u
#define THS    ((size_t)TSTEPS * HID)

typedef _Float16 f16x2v __attribute__((ext_vector_type(2)));

#if defined(__has_builtin)
# if __has_builtin(__builtin_amdgcn_fdot2)
#  define HAVE_FDOT2 1
# endif
#endif

__device__ __forceinline__ float fdot2f(u32 a, u32 b, float c) {
  f16x2v x, y;
  __builtin_memcpy(&x, &a, 4);
  __builtin_memcpy(&y, &b, 4);
#ifdef HAVE_FDOT2
  return __builtin_amdgcn_fdot2(x, y, c, false);
#else
  return c + (float)x[0] * (float)y[0] + (float)x[1] * (float)y[1];
#endif
}

__device__ __forceinline__ u32 pkh(float a, float b) {
  __half2 h = __floats2half2_rn(a, b);
  u32 r;
  __builtin_memcpy(&r, &h, 4);
  return r;
}

// nonzero iff some halfword of v equals HCAN
__device__ __forceinline__ u32 canz(u32 v) {
  u32 t = v ^ DCAN;
  return ((t - 0x00010001u) & ~t) & 0x80008000u;
}

// sum within each 32-lane half; valid in lanes 31 and 63
__device__ __forceinline__ float dpp_red32(float v) {
  int t, vi;
  __builtin_memcpy(&vi, &v, 4);
  float tf;
#define STEP(CTRL)                                                        \
  t = __builtin_amdgcn_update_dpp(0, vi, CTRL, 0xF, 0xF, true);           \
  __builtin_memcpy(&tf, &t, 4);                                           \
  v += tf;                                                                \
  __builtin_memcpy(&vi, &v, 4);
  STEP(0x111)
  STEP(0x112)
  STEP(0x114)
  STEP(0x118)
  STEP(0x142)
#undef STEP
  return v;
}

// LLC-direct 8B spin-load; exits when no fp16 halfword is the canary.
__device__ __forceinline__ uint2 spin_load8(const void* p) {
  uint2 v;
  int tries = 0;
  for (;;) {
    asm volatile("global_load_dwordx2 %0, %1, off sc0 sc1\n\ts_waitcnt vmcnt(0)"
                 : "=v"(v) : "v"(p));
    if (!(canz(v.x) | canz(v.y))) break;
    if (++tries > 2) __builtin_amdgcn_s_sleep(1);
  }
  return v;
}

// ---------------------------------------------------------------------------
// canary fill for fp16 slabs S1..S5
// ---------------------------------------------------------------------------
__global__ __launch_bounds__(256) void fill_canary(u32* __restrict__ p, long n) {
  long i = ((long)blockIdx.x * 256 + threadIdx.x) * 4;
  const long stride = (long)gridDim.x * 256 * 4;
  uint4 c;
  c.x = DCAN; c.y = DCAN; c.z = DCAN; c.w = DCAN;
  for (; i < n; i += stride) *(uint4*)(p + i) = c;
}

// ---------------------------------------------------------------------------
// lin1: S0[t][h] = fp16( lines[t] . w1[h] + b1[h] )
// ---------------------------------------------------------------------------
__global__ __launch_bounds__(256) void lin1_kernel(
    const float* __restrict__ x, const float* __restrict__ w1,
    const float* __restrict__ b1, __half* __restrict__ X0) {
  __shared__ float lt[32][65];
  __shared__ float wt[128][65];
  const int tid = threadIdx.x;
  const int t0 = blockIdx.x * 32;
  const int h0 = blockIdx.y * 128;
  const int tt0 = (tid & 7) * 4;
  const int hh0 = (tid >> 3) * 4;
  float acc[4][4] = {};
  for (int kc = 0; kc < 512; kc += 64) {
    __syncthreads();
#pragma unroll
    for (int m = 0; m < 8; ++m) {
      int e = tid + m * 256;
      int tt = e >> 6, kk = e & 63;
      int k = kc + kk;
      int aa = k >> 5, io = k & 31;
      int d = (aa == 0) ? 0 : (aa + 1);
      int st = t0 + tt - d;
      lt[tt][kk] = (st >= 0) ? x[st * 32 + io] : 0.f;
    }
#pragma unroll
    for (int m = 0; m < 32; ++m) {
      int e = tid + m * 256;
      int hh = e >> 6, kk = e & 63;
      wt[hh][kk] = w1[(size_t)(h0 + hh) * 512 + kc + kk];
    }
    __syncthreads();
    for (int kk = 0; kk < 64; ++kk) {
      float la[4], wa[4];
#pragma unroll
      for (int i = 0; i < 4; ++i) la[i] = lt[tt0 + i][kk];
#pragma unroll
      for (int j = 0; j < 4; ++j) wa[j] = wt[hh0 + j][kk];
#pragma unroll
      for (int i = 0; i < 4; ++i)
#pragma unroll
        for (int j = 0; j < 4; ++j) acc[i][j] = fmaf(la[i], wa[j], acc[i][j]);
    }
  }
#pragma unroll
  for (int i = 0; i < 4; ++i)
#pragma unroll
    for (int j = 0; j < 4; ++j)
      X0[(size_t)(t0 + tt0 + i) * HID + h0 + hh0 + j] =
          __float2half_rn(acc[i][j] + b1[h0 + hh0 + j]);
}

// ---------------------------------------------------------------------------
// persistent GRU pipeline: 5 layers x 51 blocks, 704 threads (22 half-wave
// slots). Slot s owns column h_base+s (3 rows r/z/n, 32-lane k-split).
// Gates computed slot-locally in lane 31 after the DPP reduce — one barrier
// per step, no scr round-trip. Staging/polling = round-4 proven pattern.
// ---------------------------------------------------------------------------
__global__ __launch_bounds__(704, 3) void gru_pipe(
    const float* __restrict__ wih, const float* __restrict__ whh,
    const float* __restrict__ bih, const float* __restrict__ bhh,
    __half* __restrict__ Xh) {
  const int bid = blockIdx.x;
  const int l  = bid / GSTAGE, bs = bid % GSTAGE;
  const int tid = (int)threadIdx.x;
  const int wv  = tid >> 6;          // 0..10
  const int slot = tid >> 5;         // 0..21 (half-wave slot = column)
  const int kc   = tid & 31;         // k sub-slice within slot
  const int h_base = (bs * HID) / GSTAGE;
  const int h_cnt  = ((bs + 1) * HID) / GSTAGE - h_base;   // 20 or 21
  const bool active = slot < h_cnt;

  const __half* xin = Xh + (size_t)l * THS;
  __half* hout      = Xh + (size_t)(l + 1) * THS;

  // ---- weights: 3 rows (gates r,z,n) of column h_base+slot, 32 k each ----
  // lane kc owns k = kc*8 + s*256 + j  (s=0..3, j=0..7): matches LDS layout.
  u32 wA[3][16], wB[3][16];
  const size_t lw = (size_t)l * 3 * HID * HID;
#pragma unroll
  for (int g = 0; g < 3; ++g) {
    if (active) {
      const float* rowA = wih + lw + (size_t)(g * HID + h_base + slot) * HID;
      const float* rowB = whh + lw + (size_t)(g * HID + h_base + slot) * HID;
#pragma unroll
      for (int s = 0; s < 4; ++s) {
        const float4* pa = (const float4*)(rowA + kc * 8 + s * 256);
        const float4* pb = (const float4*)(rowB + kc * 8 + s * 256);
        float4 a0 = pa[0], a1 = pa[1], b0 = pb[0], b1v = pb[1];
        wA[g][4 * s + 0] = pkh(a0.x, a0.y);
        wA[g][4 * s + 1] = pkh(a0.z, a0.w);
        wA[g][4 * s + 2] = pkh(a1.x, a1.y);
        wA[g][4 * s + 3] = pkh(a1.z, a1.w);
        wB[g][4 * s + 0] = pkh(b0.x, b0.y);
        wB[g][4 * s + 1] = pkh(b0.z, b0.w);
        wB[g][4 * s + 2] = pkh(b1v.x, b1v.y);
        wB[g][4 * s + 3] = pkh(b1v.z, b1v.w);
      }
    } else {
#pragma unroll
      for (int j = 0; j < 16; ++j) { wA[g][j] = 0u; wB[g][j] = 0u; }
    }
  }

  // gate-lane biases (lane 31 of each active slot)
  float Br = 0.f, Bz = 0.f, bin_ = 0.f, bhn_ = 0.f;
  if (kc == 31 && active) {
    const float* bi = bih + (size_t)l * 3 * HID + h_base + slot;
    const float* bh = bhh + (size_t)l * 3 * HID + h_base + slot;
    Br   = bi[0] + bh[0];
    Bz   = bi[HID] + bh[HID];
    bin_ = bi[2 * HID];
    bhn_ = bh[2 * HID];
  }

  __shared__ __align__(16) __half xbuf[3][HID];  // x triple buffer (t, t+1, t+2)
  __shared__ __align__(16) __half hbuf[2][HID];

  // prologue: waves 4-7 stage x_0, x_1
  if (wv >= 4 && wv < 8) {
    const int i = tid - 256;
    uint2 v0, v1;
    if (l == 0) {
      v0 = *(const uint2*)(xin + 4 * i);
      v1 = *(const uint2*)(xin + HID + 4 * i);
    } else {
      v0 = spin_load8(xin + 4 * i);
      v1 = spin_load8(xin + HID + 4 * i);
    }
    ((uint2*)xbuf[0])[i] = v0;
    ((uint2*)xbuf[1])[i] = v1;
  }
  __syncthreads();

  float hprev = 0.f;
  int pr = 0;  // t % 3
  for (int t = 0; t < TSTEPS; ++t) {
    const int ph = t & 1;

    // ---- (1) gi dots from xbuf[pr] — in the h-visibility shadow ----
    float ar = 0.f, az = 0.f, an = 0.f;
    {
      const uint4* cp = (const uint4*)xbuf[pr];
#pragma unroll
      for (int s = 0; s < 4; ++s) {
        uint4 c = cp[kc + 32 * s];
        ar = fdot2f(wA[0][4 * s + 0], c.x, ar);
        az = fdot2f(wA[1][4 * s + 0], c.x, az);
        an = fdot2f(wA[2][4 * s + 0], c.x, an);
        ar = fdot2f(wA[0][4 * s + 1], c.y, ar);
        az = fdot2f(wA[1][4 * s + 1], c.y, az);
        an = fdot2f(wA[2][4 * s + 1], c.y, an);
        ar = fdot2f(wA[0][4 * s + 2], c.z, ar);
        az = fdot2f(wA[1][4 * s + 2], c.z, az);
        an = fdot2f(wA[2][4 * s + 2], c.z, an);
        ar = fdot2f(wA[0][4 * s + 3], c.w, ar);
        az = fdot2f(wA[1][4 * s + 3], c.w, az);
        an = fdot2f(wA[2][4 * s + 3], c.w, an);
      }
    }
    ar = dpp_red32(ar);
    az = dpp_red32(az);
    an = dpp_red32(an);

    // ---- (2) staging: waves 0-3 h_{t-1}; waves 4-7 x_{t+2}; 8-10 none ----
    if (wv < 4) {
      uint2 v;
      if (t > 0) {
        v = spin_load8(hout + (size_t)(t - 1) * HID + 4 * tid);
      } else {
        v.x = 0u; v.y = 0u;
      }
      ((uint2*)hbuf[ph])[tid] = v;
    } else if (wv < 8) {
      const int i = tid - 256;
      int tn = t + 2;
      if (tn > TSTEPS - 1) tn = TSTEPS - 1;
      uint2 v;
      if (l == 0) v = *(const uint2*)(xin + (size_t)tn * HID + 4 * i);
      else        v = spin_load8(xin + (size_t)tn * HID + 4 * i);
      int pw = pr + 2;
      if (pw >= 3) pw -= 3;
      ((uint2*)xbuf[pw])[i] = v;
    }
    __syncthreads();  // the only barrier per step

    // ---- (3) gh dots from hbuf[ph] ----
    float br = 0.f, bz = 0.f, bn = 0.f;
    {
      const uint4* cp = (const uint4*)hbuf[ph];
#pragma unroll
      for (int s = 0; s < 4; ++s) {
        uint4 c = cp[kc + 32 * s];
        br = fdot2f(wB[0][4 * s + 0], c.x, br);
        bz = fdot2f(wB[1][4 * s + 0], c.x, bz);
        bn = fdot2f(wB[2][4 * s + 0], c.x, bn);
        br = fdot2f(wB[0][4 * s + 1], c.y, br);
        bz = fdot2f(wB[1][4 * s + 1], c.y, bz);
        bn = fdot2f(wB[2][4 * s + 1], c.y, bn);
        br = fdot2f(wB[0][4 * s + 2], c.z, br);
        bz = fdot2f(wB[1][4 * s + 2], c.z, bz);
        bn = fdot2f(wB[2][4 * s + 2], c.z, bn);
        br = fdot2f(wB[0][4 * s + 3], c.w, br);
        bz = fdot2f(wB[1][4 * s + 3], c.w, bz);
        bn = fdot2f(wB[2][4 * s + 3], c.w, bn);
      }
    }
    br = dpp_red32(br);
    bz = dpp_red32(bz);
    bn = dpp_red32(bn);

    // ---- (4) gates, slot-local in lane 31; publish h fp16 LLC-direct ----
    if (kc == 31 && active) {
      float rr = 1.f / (1.f + __expf(-(ar + br + Br)));
      float zz = 1.f / (1.f + __expf(-(az + bz + Bz)));
      float targ = (an + bin_) + rr * (bn + bhn_);
      targ = fminf(fmaxf(targ, -15.f), 15.f);
      float e2 = __expf(2.f * targ);
      float nn = (e2 - 1.f) / (e2 + 1.f);
      float hv = (1.f - zz) * nn + zz * hprev;
      hprev = hv;
      u32 hb = (u32)__half_as_ushort(__float2half_rn(hv));
      const __half* dst = hout + (size_t)t * HID + h_base + slot;
      asm volatile("global_store_short %0, %1, off sc0 sc1" :: "v"(dst), "v"(hb));
    }

    pr += 1;
    if (pr >= 3) pr -= 3;
  }
}

// ---------------------------------------------------------------------------
// lin2: out[o,t,io] = h5[t] . w2[o*32+io] + b2   (h5 = S5, fp16)
// ---------------------------------------------------------------------------
__global__ __launch_bounds__(256) void lin2_kernel(
    const __half* __restrict__ h5, const float* __restrict__ w2,
    const float* __restrict__ b2, float* __restrict__ out) {
  __shared__ float at[64][65];
  __shared__ float bt[64][65];
  const int tid = threadIdx.x;
  const int t0 = blockIdx.x * 64;
  const int j0 = blockIdx.y * 64;
  const int tt0 = (tid & 15) * 4;
  const int jj0 = (tid >> 4) * 4;
  float acc[4][4] = {};
  for (int kc = 0; kc < 1024; kc += 64) {
    __syncthreads();
#pragma unroll
    for (int m = 0; m < 16; ++m) {
      int e = tid + m * 256;
      int tt = e >> 6, kk = e & 63;
      at[tt][kk] = __half2float(h5[(size_t)(t0 + tt) * HID + kc + kk]);
    }
#pragma unroll
    for (int m = 0; m < 16; ++m) {
      int e = tid + m * 256;
      int jj = e >> 6, kk = e & 63;
      bt[jj][kk] = w2[(size_t)(j0 + jj) * HID + kc + kk];
    }
    __syncthreads();
    for (int kk = 0; kk < 64; ++kk) {
      float la[4], wa[4];
#pragma unroll
      for (int i = 0; i < 4; ++i) la[i] = at[tt0 + i][kk];
#pragma unroll
      for (int j = 0; j < 4; ++j) wa[j] = bt[jj0 + j][kk];
#pragma unroll
      for (int i = 0; i < 4; ++i)
#pragma unroll
        for (int j = 0; j < 4; ++j) acc[i][j] = fmaf(la[i], wa[j], acc[i][j]);
    }
  }
#pragma unroll
  for (int i = 0; i < 4; ++i)
#pragma unroll
    for (int jq = 0; jq < 4; ++jq) {
      int j = j0 + jj0 + jq;
      out[(size_t)(j >> 5) * (TSTEPS * 32) + (size_t)(t0 + tt0 + i) * 32 + (j & 31)] =
          acc[i][jq] + b2[j];
    }
}

extern "C" void kernel_launch(void* const* d_in, const int* in_sizes, int n_in,
                              void* d_out, int out_size, void* d_ws, size_t ws_size,
                              hipStream_t stream) {
  const float* x   = (const float*)d_in[0];
  const float* w1  = (const float*)d_in[1];
  const float* b1  = (const float*)d_in[2];
  const float* wih = (const float*)d_in[3];
  const float* whh = (const float*)d_in[4];
  const float* bih = (const float*)d_in[5];
  const float* bhh = (const float*)d_in[6];
  const float* w2  = (const float*)d_in[7];
  const float* b2  = (const float*)d_in[8];
  float* out = (float*)d_out;

  __half* Xh = (__half*)d_ws;  // 6 fp16 slabs S0..S5 of [T][H] (24 MB)

  // arm canaries in S1..S5 (re-armed every launch/replay)
  fill_canary<<<1280, 256, 0, stream>>>((u32*)(Xh + THS),
                                        (long)NDEPTH * (long)THS / 2);
  lin1_kernel<<<dim3(64, 8), 256, 0, stream>>>(x, w1, b1, Xh);
  gru_pipe<<<NBLOCKS, 704, 0, stream>>>(wih, whh, bih, bhh, Xh);
  lin2_kernel<<<dim3(32, 4), 256, 0, stream>>>(Xh + (size_t)NDEPTH * THS,
                                               w2, b2, out);
}

// Round 9
// 4427.709 us; speedup vs baseline: 1.6494x; 1.6494x over previous
//
#include <hip/hip_runtime.h>
#include <hip/hip_fp16.h>

typedef unsigned int u32;

#define TSTEPS 2048
#define HID    1024
#define NDEPTH 5
#define GSTAGE 51
#define NBLOCKS (NDEPTH * GSTAGE)   // 255 blocks, 1 per CU
#define HCAN   0x7c00u              // fp16 +inf: unreachable by activations
#define DCAN   0x7c007c00u
#define THS    ((size_t)TSTEPS * HID)

typedef _Float16 f16x2v __attribute__((ext_vector_type(2)));

#if defined(__has_builtin)
# if __has_builtin(__builtin_amdgcn_fdot2)
#  define HAVE_FDOT2 1
# endif
#endif

__device__ __forceinline__ float fdot2f(u32 a, u32 b, float c) {
  f16x2v x, y;
  __builtin_memcpy(&x, &a, 4);
  __builtin_memcpy(&y, &b, 4);
#ifdef HAVE_FDOT2
  return __builtin_amdgcn_fdot2(x, y, c, false);
#else
  return c + (float)x[0] * (float)y[0] + (float)x[1] * (float)y[1];
#endif
}

// VGPR-pinned dot2 (non-volatile asm: schedulable, but operands must be
// architectural VGPRs -> biases the allocator to keep gh weights out of AGPRs)
__device__ __forceinline__ float fdot2a(u32 w, u32 h, float acc) {
  float d = acc;
  asm("v_dot2_f32_f16 %0, %1, %2, %0" : "+v"(d) : "v"(w), "v"(h));
  return d;
}

__device__ __forceinline__ u32 pkh(float a, float b) {
  __half2 h = __floats2half2_rn(a, b);
  u32 r;
  __builtin_memcpy(&r, &h, 4);
  return r;
}

// nonzero iff some halfword of v equals HCAN
__device__ __forceinline__ u32 canz(u32 v) {
  u32 t = v ^ DCAN;
  return ((t - 0x00010001u) & ~t) & 0x80008000u;
}

// sum within each 32-lane half; valid in lanes 31 and 63
__device__ __forceinline__ float dpp_red32(float v) {
  int t, vi;
  __builtin_memcpy(&vi, &v, 4);
  float tf;
#define STEP(CTRL)                                                        \
  t = __builtin_amdgcn_update_dpp(0, vi, CTRL, 0xF, 0xF, true);           \
  __builtin_memcpy(&tf, &t, 4);                                           \
  v += tf;                                                                \
  __builtin_memcpy(&vi, &v, 4);
  STEP(0x111)
  STEP(0x112)
  STEP(0x114)
  STEP(0x118)
  STEP(0x142)
#undef STEP
  return v;
}

// LLC-direct 8B spin-load; exits when no fp16 halfword is the canary.
// vmcnt(0) per poll: the only compiler-sound spin (round-8 post-mortem).
__device__ __forceinline__ uint2 spin_load8(const void* p) {
  uint2 v;
  int tries = 0;
  for (;;) {
    asm volatile("global_load_dwordx2 %0, %1, off sc0 sc1\n\ts_waitcnt vmcnt(0)"
                 : "=v"(v) : "v"(p));
    if (!(canz(v.x) | canz(v.y))) break;
    if (++tries > 2) __builtin_amdgcn_s_sleep(1);
  }
  return v;
}

// ---------------------------------------------------------------------------
// canary fill for fp16 slabs S1..S5
// ---------------------------------------------------------------------------
__global__ __launch_bounds__(256) void fill_canary(u32* __restrict__ p, long n) {
  long i = ((long)blockIdx.x * 256 + threadIdx.x) * 4;
  const long stride = (long)gridDim.x * 256 * 4;
  uint4 c;
  c.x = DCAN; c.y = DCAN; c.z = DCAN; c.w = DCAN;
  for (; i < n; i += stride) *(uint4*)(p + i) = c;
}

// ---------------------------------------------------------------------------
// lin1: S0[t][h] = fp16( lines[t] . w1[h] + b1[h] )
// ---------------------------------------------------------------------------
__global__ __launch_bounds__(256) void lin1_kernel(
    const float* __restrict__ x, const float* __restrict__ w1,
    const float* __restrict__ b1, __half* __restrict__ X0) {
  __shared__ float lt[32][65];
  __shared__ float wt[128][65];
  const int tid = threadIdx.x;
  const int t0 = blockIdx.x * 32;
  const int h0 = blockIdx.y * 128;
  const int tt0 = (tid & 7) * 4;
  const int hh0 = (tid >> 3) * 4;
  float acc[4][4] = {};
  for (int kc = 0; kc < 512; kc += 64) {
    __syncthreads();
#pragma unroll
    for (int m = 0; m < 8; ++m) {
      int e = tid + m * 256;
      int tt = e >> 6, kk = e & 63;
      int k = kc + kk;
      int aa = k >> 5, io = k & 31;
      int d = (aa == 0) ? 0 : (aa + 1);
      int st = t0 + tt - d;
      lt[tt][kk] = (st >= 0) ? x[st * 32 + io] : 0.f;
    }
#pragma unroll
    for (int m = 0; m < 32; ++m) {
      int e = tid + m * 256;
      int hh = e >> 6, kk = e & 63;
      wt[hh][kk] = w1[(size_t)(h0 + hh) * 512 + kc + kk];
    }
    __syncthreads();
    for (int kk = 0; kk < 64; ++kk) {
      float la[4], wa[4];
#pragma unroll
      for (int i = 0; i < 4; ++i) la[i] = lt[tt0 + i][kk];
#pragma unroll
      for (int j = 0; j < 4; ++j) wa[j] = wt[hh0 + j][kk];
#pragma unroll
      for (int i = 0; i < 4; ++i)
#pragma unroll
        for (int j = 0; j < 4; ++j) acc[i][j] = fmaf(la[i], wa[j], acc[i][j]);
    }
  }
#pragma unroll
  for (int i = 0; i < 4; ++i)
#pragma unroll
    for (int j = 0; j < 4; ++j)
      X0[(size_t)(t0 + tt0 + i) * HID + h0 + hh0 + j] =
          __float2half_rn(acc[i][j] + b1[h0 + hh0 + j]);
}

// ---------------------------------------------------------------------------
// persistent GRU pipeline (round-4 proven structure):
// 5 layers x 51 blocks, fp16 weights register-resident, canary dataflow.
// gh dots via VGPR-pinned asm dot2 (keep the critical phase out of AGPRs).
// ---------------------------------------------------------------------------
__global__ __launch_bounds__(512, 2) void gru_pipe(
    const float* __restrict__ wih, const float* __restrict__ whh,
    const float* __restrict__ bih, const float* __restrict__ bhh,
    __half* __restrict__ Xh) {
  const int bid = blockIdx.x;
  const int l  = bid / GSTAGE, bs = bid % GSTAGE;
  const int tid = (int)threadIdx.x;
  const int lane = tid & 63;
  const int wv   = tid >> 6;           // 0..7
  const int half = lane >> 5;
  const int kc   = lane & 31;
  const int RG   = 2 * wv + half;      // 0..15 row-group

  const int h_base = (bs * HID) / GSTAGE;
  const int h_cnt  = ((bs + 1) * HID) / GSTAGE - h_base;   // 20 or 21
  const int ndot = 3 * h_cnt;                              // <= 63

  // --- weights: 4 gi rows + 4 gh rows, 32 k each, fp16 packed (128 regs) ---
  const size_t lw = (size_t)l * 3 * HID * HID;
  u32 wA[4][16], wB[4][16];
#pragma unroll
  for (int r = 0; r < 4; ++r) {
    const int d = 4 * RG + r;
    if (d < ndot) {
      const int jj = d / 3, g = d % 3;
      const float* rowA = wih + lw + (size_t)(g * HID + h_base + jj) * HID;
      const float* rowB = whh + lw + (size_t)(g * HID + h_base + jj) * HID;
#pragma unroll
      for (int s = 0; s < 4; ++s) {
        const float4* sa = (const float4*)(rowA + kc * 8 + s * 256);
        const float4* sb = (const float4*)(rowB + kc * 8 + s * 256);
        float4 a0 = sa[0], a1 = sa[1], b0 = sb[0], b1v = sb[1];
        wA[r][s * 4 + 0] = pkh(a0.x, a0.y);
        wA[r][s * 4 + 1] = pkh(a0.z, a0.w);
        wA[r][s * 4 + 2] = pkh(a1.x, a1.y);
        wA[r][s * 4 + 3] = pkh(a1.z, a1.w);
        wB[r][s * 4 + 0] = pkh(b0.x, b0.y);
        wB[r][s * 4 + 1] = pkh(b0.z, b0.w);
        wB[r][s * 4 + 2] = pkh(b1v.x, b1v.y);
        wB[r][s * 4 + 3] = pkh(b1v.z, b1v.w);
      }
    } else {
#pragma unroll
      for (int i = 0; i < 16; ++i) { wA[r][i] = 0u; wB[r][i] = 0u; }
    }
  }

  float b6[6] = {0.f, 0.f, 0.f, 0.f, 0.f, 0.f};
  if (wv == 0 && lane < h_cnt) {
#pragma unroll
    for (int g = 0; g < 3; ++g) {
      b6[g]     = bih[(size_t)l * 3 * HID + g * HID + h_base + lane];
      b6[3 + g] = bhh[(size_t)l * 3 * HID + g * HID + h_base + lane];
    }
  }

  __shared__ __align__(16) __half xbuf[2][HID];
  __shared__ __align__(16) __half hbuf[2][HID];
  __shared__ __align__(16) float scr[2][128];

  const __half* in = Xh + (size_t)l * THS;
  __half* out      = Xh + (size_t)(l + 1) * THS;

  // --- prologue: stage x_0 into xbuf[0] (waves 4-7) ---
  if (wv >= 4) {
    const int i = tid - 256;
    uint2 v;
    if (l == 0) v = *(const uint2*)(in + 4 * i);
    else        v = spin_load8(in + 4 * i);
    ((uint2*)xbuf[0])[i] = v;
  }
  float hprev = 0.f;
  __syncthreads();

  for (int t = 0; t < TSTEPS; ++t) {
    const int p = t & 1;

    // ---- (1) gi dots from xbuf[p] — in the h-visibility shadow ----
    {
      const uint4* cp = (const uint4*)xbuf[p];
      float a0 = 0.f, a1 = 0.f, a2 = 0.f, a3 = 0.f;
#pragma unroll
      for (int s = 0; s < 4; ++s) {
        uint4 c = cp[kc + 32 * s];
        a0 = fdot2f(wA[0][4 * s + 0], c.x, a0);
        a1 = fdot2f(wA[1][4 * s + 0], c.x, a1);
        a2 = fdot2f(wA[2][4 * s + 0], c.x, a2);
        a3 = fdot2f(wA[3][4 * s + 0], c.x, a3);
        a0 = fdot2f(wA[0][4 * s + 1], c.y, a0);
        a1 = fdot2f(wA[1][4 * s + 1], c.y, a1);
        a2 = fdot2f(wA[2][4 * s + 1], c.y, a2);
        a3 = fdot2f(wA[3][4 * s + 1], c.y, a3);
        a0 = fdot2f(wA[0][4 * s + 2], c.z, a0);
        a1 = fdot2f(wA[1][4 * s + 2], c.z, a1);
        a2 = fdot2f(wA[2][4 * s + 2], c.z, a2);
        a3 = fdot2f(wA[3][4 * s + 2], c.z, a3);
        a0 = fdot2f(wA[0][4 * s + 3], c.w, a0);
        a1 = fdot2f(wA[1][4 * s + 3], c.w, a1);
        a2 = fdot2f(wA[2][4 * s + 3], c.w, a2);
        a3 = fdot2f(wA[3][4 * s + 3], c.w, a3);
      }
      a0 = dpp_red32(a0);
      a1 = dpp_red32(a1);
      a2 = dpp_red32(a2);
      a3 = dpp_red32(a3);
      if ((lane & 31) == 31) {
        float4 s4; s4.x = a0; s4.y = a1; s4.z = a2; s4.w = a3;
        *((float4*)&scr[p][4 * RG]) = s4;
      }
    }

    // ---- (2) waves 0-3: spin-stage h_{t-1}; waves 4-7: prefetch x_{t+1} ----
    if (wv < 4) {
      uint2 v;
      if (t > 0) {
        v = spin_load8(out + (size_t)(t - 1) * HID + 4 * tid);
      } else {
        v.x = 0u; v.y = 0u;
      }
      ((uint2*)hbuf[p])[tid] = v;
    } else {
      const int i = tid - 256;
      const int tn = (t + 1 < TSTEPS) ? (t + 1) : (TSTEPS - 1);
      uint2 v;
      if (l == 0) v = *(const uint2*)(in + (size_t)tn * HID + 4 * i);
      else        v = spin_load8(in + (size_t)tn * HID + 4 * i);
      ((uint2*)xbuf[p ^ 1])[i] = v;
    }
    __syncthreads();   // (c)

    // ---- (3) gh dots from hbuf[p] — VGPR-pinned asm dot2 ----
    {
      const uint4* cp = (const uint4*)hbuf[p];
      float a0 = 0.f, a1 = 0.f, a2 = 0.f, a3 = 0.f;
#pragma unroll
      for (int s = 0; s < 4; ++s) {
        uint4 c = cp[kc + 32 * s];
        a0 = fdot2a(wB[0][4 * s + 0], c.x, a0);
        a1 = fdot2a(wB[1][4 * s + 0], c.x, a1);
        a2 = fdot2a(wB[2][4 * s + 0], c.x, a2);
        a3 = fdot2a(wB[3][4 * s + 0], c.x, a3);
        a0 = fdot2a(wB[0][4 * s + 1], c.y, a0);
        a1 = fdot2a(wB[1][4 * s + 1], c.y, a1);
        a2 = fdot2a(wB[2][4 * s + 1], c.y, a2);
        a3 = fdot2a(wB[3][4 * s + 1], c.y, a3);
        a0 = fdot2a(wB[0][4 * s + 2], c.z, a0);
        a1 = fdot2a(wB[1][4 * s + 2], c.z, a1);
        a2 = fdot2a(wB[2][4 * s + 2], c.z, a2);
        a3 = fdot2a(wB[3][4 * s + 2], c.z, a3);
        a0 = fdot2a(wB[0][4 * s + 3], c.w, a0);
        a1 = fdot2a(wB[1][4 * s + 3], c.w, a1);
        a2 = fdot2a(wB[2][4 * s + 3], c.w, a2);
        a3 = fdot2a(wB[3][4 * s + 3], c.w, a3);
      }
      a0 = dpp_red32(a0);
      a1 = dpp_red32(a1);
      a2 = dpp_red32(a2);
      a3 = dpp_red32(a3);
      if ((lane & 31) == 31) {
        float4 s4; s4.x = a0; s4.y = a1; s4.z = a2; s4.w = a3;
        *((float4*)&scr[p][64 + 4 * RG]) = s4;
      }
    }
    __syncthreads();   // (d)

    // ---- (4) gates on wave 0; publish h_t fp16, LLC-direct ----
    if (wv == 0 && lane < h_cnt) {
      __builtin_amdgcn_s_setprio(1);
      const int jj = lane;
      float ir = scr[p][3 * jj + 0] + b6[0];
      float iz = scr[p][3 * jj + 1] + b6[1];
      float in_ = scr[p][3 * jj + 2] + b6[2];
      float hr = scr[p][64 + 3 * jj + 0] + b6[3];
      float hz = scr[p][64 + 3 * jj + 1] + b6[4];
      float hn = scr[p][64 + 3 * jj + 2] + b6[5];
      float rr = 1.f / (1.f + __expf(-(ir + hr)));
      float zz = 1.f / (1.f + __expf(-(iz + hz)));
      float targ = in_ + rr * hn;
      targ = fminf(fmaxf(targ, -15.f), 15.f);
      float e2 = __expf(2.f * targ);
      float nn = (e2 - 1.f) / (e2 + 1.f);
      float hv = (1.f - zz) * nn + zz * hprev;
      hprev = hv;
      u32 hb = (u32)__half_as_ushort(__float2half_rn(hv));
      const __half* dst = out + (size_t)t * HID + h_base + jj;
      asm volatile("global_store_short %0, %1, off sc0 sc1" :: "v"(dst), "v"(hb));
      __builtin_amdgcn_s_setprio(0);
    }
  }
}

// ---------------------------------------------------------------------------
// lin2: out[o,t,io] = h5[t] . w2[o*32+io] + b2   (h5 = S5, fp16)
// ---------------------------------------------------------------------------
__global__ __launch_bounds__(256) void lin2_kernel(
    const __half* __restrict__ h5, const float* __restrict__ w2,
    const float* __restrict__ b2, float* __restrict__ out) {
  __shared__ float at[64][65];
  __shared__ float bt[64][65];
  const int tid = threadIdx.x;
  const int t0 = blockIdx.x * 64;
  const int j0 = blockIdx.y * 64;
  const int tt0 = (tid & 15) * 4;
  const int jj0 = (tid >> 4) * 4;
  float acc[4][4] = {};
  for (int kc = 0; kc < 1024; kc += 64) {
    __syncthreads();
#pragma unroll
    for (int m = 0; m < 16; ++m) {
      int e = tid + m * 256;
      int tt = e >> 6, kk = e & 63;
      at[tt][kk] = __half2float(h5[(size_t)(t0 + tt) * HID + kc + kk]);
    }
#pragma unroll
    for (int m = 0; m < 16; ++m) {
      int e = tid + m * 256;
      int jj = e >> 6, kk = e & 63;
      bt[jj][kk] = w2[(size_t)(j0 + jj) * HID + kc + kk];
    }
    __syncthreads();
    for (int kk = 0; kk < 64; ++kk) {
      float la[4], wa[4];
#pragma unroll
      for (int i = 0; i < 4; ++i) la[i] = at[tt0 + i][kk];
#pragma unroll
      for (int j = 0; j < 4; ++j) wa[j] = bt[jj0 + j][kk];
#pragma unroll
      for (int i = 0; i < 4; ++i)
#pragma unroll
        for (int j = 0; j < 4; ++j) acc[i][j] = fmaf(la[i], wa[j], acc[i][j]);
    }
  }
#pragma unroll
  for (int i = 0; i < 4; ++i)
#pragma unroll
    for (int jq = 0; jq < 4; ++jq) {
      int j = j0 + jj0 + jq;
      out[(size_t)(j >> 5) * (TSTEPS * 32) + (size_t)(t0 + tt0 + i) * 32 + (j & 31)] =
          acc[i][jq] + b2[j];
    }
}

extern "C" void kernel_launch(void* const* d_in, const int* in_sizes, int n_in,
                              void* d_out, int out_size, void* d_ws, size_t ws_size,
                              hipStream_t stream) {
  const float* x   = (const float*)d_in[0];
  const float* w1  = (const float*)d_in[1];
  const float* b1  = (const float*)d_in[2];
  const float* wih = (const float*)d_in[3];
  const float* whh = (const float*)d_in[4];
  const float* bih = (const float*)d_in[5];
  const float* bhh = (const float*)d_in[6];
  const float* w2  = (const float*)d_in[7];
  const float* b2  = (const float*)d_in[8];
  float* out = (float*)d_out;

  __half* Xh = (__half*)d_ws;  // 6 fp16 slabs S0..S5 of [T][H] (24 MB)

  // arm canaries in S1..S5 (re-armed every launch/replay)
  fill_canary<<<1280, 256, 0, stream>>>((u32*)(Xh + THS),
                                        (long)NDEPTH * (long)THS / 2);
  lin1_kernel<<<dim3(64, 8), 256, 0, stream>>>(x, w1, b1, Xh);
  gru_pipe<<<NBLOCKS, 512, 0, stream>>>(wih, whh, bih, bhh, Xh);
  lin2_kernel<<<dim3(32, 4), 256, 0, stream>>>(Xh + (size_t)NDEPTH * THS,
                                               w2, b2, out);
}

// Round 10
// 3292.735 us; speedup vs baseline: 2.2179x; 1.3447x over previous
//
#include <hip/hip_runtime.h>
#include <hip/hip_fp16.h>

typedef unsigned int u32;

#define TSTEPS 2048
#define HID    1024
#define NDEPTH 5
#define GSTAGE 51
#define NBLOCKS (NDEPTH * GSTAGE)   // 255 blocks, 1 per CU
#define HCAN   0x7c00u              // fp16 +inf: unreachable by activations
#define DCAN   0x7c007c00u
#define THS    ((size_t)TSTEPS * HID)

typedef _Float16 f16x2v __attribute__((ext_vector_type(2)));

#if defined(__has_builtin)
# if __has_builtin(__builtin_amdgcn_fdot2)
#  define HAVE_FDOT2 1
# endif
#endif

__device__ __forceinline__ float fdot2f(u32 a, u32 b, float c) {
  f16x2v x, y;
  __builtin_memcpy(&x, &a, 4);
  __builtin_memcpy(&y, &b, 4);
#ifdef HAVE_FDOT2
  return __builtin_amdgcn_fdot2(x, y, c, false);
#else
  return c + (float)x[0] * (float)y[0] + (float)x[1] * (float)y[1];
#endif
}

__device__ __forceinline__ u32 pkh(float a, float b) {
  __half2 h = __floats2half2_rn(a, b);
  u32 r;
  __builtin_memcpy(&r, &h, 4);
  return r;
}

// nonzero iff some halfword of v equals HCAN
__device__ __forceinline__ u32 canz(u32 v) {
  u32 t = v ^ DCAN;
  return ((t - 0x00010001u) & ~t) & 0x80008000u;
}

// sum within each 32-lane half; valid in lanes 31 and 63
__device__ __forceinline__ float dpp_red32(float v) {
  int t, vi;
  __builtin_memcpy(&vi, &v, 4);
  float tf;
#define STEP(CTRL)                                                        \
  t = __builtin_amdgcn_update_dpp(0, vi, CTRL, 0xF, 0xF, true);           \
  __builtin_memcpy(&tf, &t, 4);                                           \
  v += tf;                                                                \
  __builtin_memcpy(&vi, &v, 4);
  STEP(0x111)
  STEP(0x112)
  STEP(0x114)
  STEP(0x118)
  STEP(0x142)
#undef STEP
  return v;
}

// LLC-direct 8B spin-load; exits when no fp16 halfword is the canary.
// vmcnt(0) per poll: the only compiler-sound spin (round-8 post-mortem).
__device__ __forceinline__ uint2 spin_load8(const void* p) {
  uint2 v;
  int tries = 0;
  for (;;) {
    asm volatile("global_load_dwordx2 %0, %1, off sc0 sc1\n\ts_waitcnt vmcnt(0)"
                 : "=v"(v) : "v"(p));
    if (!(canz(v.x) | canz(v.y))) break;
    if (++tries > 2) __builtin_amdgcn_s_sleep(1);
  }
  return v;
}

// ---------------------------------------------------------------------------
// canary fill for fp16 slabs S1..S5
// ---------------------------------------------------------------------------
__global__ __launch_bounds__(256) void fill_canary(u32* __restrict__ p, long n) {
  long i = ((long)blockIdx.x * 256 + threadIdx.x) * 4;
  const long stride = (long)gridDim.x * 256 * 4;
  uint4 c;
  c.x = DCAN; c.y = DCAN; c.z = DCAN; c.w = DCAN;
  for (; i < n; i += stride) *(uint4*)(p + i) = c;
}

// ---------------------------------------------------------------------------
// lin1: S0[t][h] = fp16( lines[t] . w1[h] + b1[h] )
// ---------------------------------------------------------------------------
__global__ __launch_bounds__(256) void lin1_kernel(
    const float* __restrict__ x, const float* __restrict__ w1,
    const float* __restrict__ b1, __half* __restrict__ X0) {
  __shared__ float lt[32][65];
  __shared__ float wt[128][65];
  const int tid = threadIdx.x;
  const int t0 = blockIdx.x * 32;
  const int h0 = blockIdx.y * 128;
  const int tt0 = (tid & 7) * 4;
  const int hh0 = (tid >> 3) * 4;
  float acc[4][4] = {};
  for (int kc = 0; kc < 512; kc += 64) {
    __syncthreads();
#pragma unroll
    for (int m = 0; m < 8; ++m) {
      int e = tid + m * 256;
      int tt = e >> 6, kk = e & 63;
      int k = kc + kk;
      int aa = k >> 5, io = k & 31;
      int d = (aa == 0) ? 0 : (aa + 1);
      int st = t0 + tt - d;
      lt[tt][kk] = (st >= 0) ? x[st * 32 + io] : 0.f;
    }
#pragma unroll
    for (int m = 0; m < 32; ++m) {
      int e = tid + m * 256;
      int hh = e >> 6, kk = e & 63;
      wt[hh][kk] = w1[(size_t)(h0 + hh) * 512 + kc + kk];
    }
    __syncthreads();
    for (int kk = 0; kk < 64; ++kk) {
      float la[4], wa[4];
#pragma unroll
      for (int i = 0; i < 4; ++i) la[i] = lt[tt0 + i][kk];
#pragma unroll
      for (int j = 0; j < 4; ++j) wa[j] = wt[hh0 + j][kk];
#pragma unroll
      for (int i = 0; i < 4; ++i)
#pragma unroll
        for (int j = 0; j < 4; ++j) acc[i][j] = fmaf(la[i], wa[j], acc[i][j]);
    }
  }
#pragma unroll
  for (int i = 0; i < 4; ++i)
#pragma unroll
    for (int j = 0; j < 4; ++j)
      X0[(size_t)(t0 + tt0 + i) * HID + h0 + hh0 + j] =
          __float2half_rn(acc[i][j] + b1[h0 + hh0 + j]);
}

// ---------------------------------------------------------------------------
// persistent GRU pipeline (round-4 proven structure):
//  + gates distributed across waves 0-3 (shorter serial tail)
//  + x-prefetch ring depth 3 (decouple inter-layer jitter)
// ---------------------------------------------------------------------------
__global__ __launch_bounds__(512, 2) void gru_pipe(
    const float* __restrict__ wih, const float* __restrict__ whh,
    const float* __restrict__ bih, const float* __restrict__ bhh,
    __half* __restrict__ Xh) {
  const int bid = blockIdx.x;
  const int l  = bid / GSTAGE, bs = bid % GSTAGE;
  const int tid = (int)threadIdx.x;
  const int lane = tid & 63;
  const int wv   = tid >> 6;           // 0..7
  const int half = lane >> 5;
  const int kc   = lane & 31;
  const int RG   = 2 * wv + half;      // 0..15 row-group

  const int h_base = (bs * HID) / GSTAGE;
  const int h_cnt  = ((bs + 1) * HID) / GSTAGE - h_base;   // 20 or 21
  const int ndot = 3 * h_cnt;                              // <= 63

  // --- weights: 4 gi rows + 4 gh rows, 32 k each, fp16 packed (128 regs) ---
  const size_t lw = (size_t)l * 3 * HID * HID;
  u32 wA[4][16], wB[4][16];
#pragma unroll
  for (int r = 0; r < 4; ++r) {
    const int d = 4 * RG + r;
    if (d < ndot) {
      const int jj = d / 3, g = d % 3;
      const float* rowA = wih + lw + (size_t)(g * HID + h_base + jj) * HID;
      const float* rowB = whh + lw + (size_t)(g * HID + h_base + jj) * HID;
#pragma unroll
      for (int s = 0; s < 4; ++s) {
        const float4* sa = (const float4*)(rowA + kc * 8 + s * 256);
        const float4* sb = (const float4*)(rowB + kc * 8 + s * 256);
        float4 a0 = sa[0], a1 = sa[1], b0 = sb[0], b1v = sb[1];
        wA[r][s * 4 + 0] = pkh(a0.x, a0.y);
        wA[r][s * 4 + 1] = pkh(a0.z, a0.w);
        wA[r][s * 4 + 2] = pkh(a1.x, a1.y);
        wA[r][s * 4 + 3] = pkh(a1.z, a1.w);
        wB[r][s * 4 + 0] = pkh(b0.x, b0.y);
        wB[r][s * 4 + 1] = pkh(b0.z, b0.w);
        wB[r][s * 4 + 2] = pkh(b1v.x, b1v.y);
        wB[r][s * 4 + 3] = pkh(b1v.z, b1v.w);
      }
    } else {
#pragma unroll
      for (int i = 0; i < 16; ++i) { wA[r][i] = 0u; wB[r][i] = 0u; }
    }
  }

  // gate ownership: wave w (0-3), lane gl (0-5) owns column jj = 6*w + gl
  const int jjg = 6 * wv + lane;       // valid when wv<4 && lane<6
  const bool gate_owner = (wv < 4) && (lane < 6) && (jjg < h_cnt);
  float b6[6] = {0.f, 0.f, 0.f, 0.f, 0.f, 0.f};
  if (gate_owner) {
#pragma unroll
    for (int g = 0; g < 3; ++g) {
      b6[g]     = bih[(size_t)l * 3 * HID + g * HID + h_base + jjg];
      b6[3 + g] = bhh[(size_t)l * 3 * HID + g * HID + h_base + jjg];
    }
  }

  __shared__ __align__(16) __half xbuf[3][HID];   // ring: slots t%3
  __shared__ __align__(16) __half hbuf[2][HID];
  __shared__ __align__(16) float scr[2][128];

  const __half* in = Xh + (size_t)l * THS;
  __half* out      = Xh + (size_t)(l + 1) * THS;

  // --- prologue: waves 4-7 stage x_0 -> slot0, x_1 -> slot1 ---
  if (wv >= 4) {
    const int i = tid - 256;
    uint2 v0, v1;
    if (l == 0) {
      v0 = *(const uint2*)(in + 4 * i);
      v1 = *(const uint2*)(in + HID + 4 * i);
    } else {
      v0 = spin_load8(in + 4 * i);
      v1 = spin_load8(in + HID + 4 * i);
    }
    ((uint2*)xbuf[0])[i] = v0;
    ((uint2*)xbuf[1])[i] = v1;
  }
  float hprev = 0.f;
  __syncthreads();

  int rx = 0;  // t % 3
  for (int t = 0; t < TSTEPS; ++t) {
    const int p = t & 1;

    // ---- (1) gi dots from xbuf[rx] — in the h-visibility shadow ----
    {
      const uint4* cp = (const uint4*)xbuf[rx];
      float a0 = 0.f, a1 = 0.f, a2 = 0.f, a3 = 0.f;
#pragma unroll
      for (int s = 0; s < 4; ++s) {
        uint4 c = cp[kc + 32 * s];
        a0 = fdot2f(wA[0][4 * s + 0], c.x, a0);
        a1 = fdot2f(wA[1][4 * s + 0], c.x, a1);
        a2 = fdot2f(wA[2][4 * s + 0], c.x, a2);
        a3 = fdot2f(wA[3][4 * s + 0], c.x, a3);
        a0 = fdot2f(wA[0][4 * s + 1], c.y, a0);
        a1 = fdot2f(wA[1][4 * s + 1], c.y, a1);
        a2 = fdot2f(wA[2][4 * s + 1], c.y, a2);
        a3 = fdot2f(wA[3][4 * s + 1], c.y, a3);
        a0 = fdot2f(wA[0][4 * s + 2], c.z, a0);
        a1 = fdot2f(wA[1][4 * s + 2], c.z, a1);
        a2 = fdot2f(wA[2][4 * s + 2], c.z, a2);
        a3 = fdot2f(wA[3][4 * s + 2], c.z, a3);
        a0 = fdot2f(wA[0][4 * s + 3], c.w, a0);
        a1 = fdot2f(wA[1][4 * s + 3], c.w, a1);
        a2 = fdot2f(wA[2][4 * s + 3], c.w, a2);
        a3 = fdot2f(wA[3][4 * s + 3], c.w, a3);
      }
      a0 = dpp_red32(a0);
      a1 = dpp_red32(a1);
      a2 = dpp_red32(a2);
      a3 = dpp_red32(a3);
      if ((lane & 31) == 31) {
        float4 s4; s4.x = a0; s4.y = a1; s4.z = a2; s4.w = a3;
        *((float4*)&scr[p][4 * RG]) = s4;
      }
    }

    // ---- (2) waves 0-3: spin-stage h_{t-1}; waves 4-7: prefetch x_{t+2} ----
    if (wv < 4) {
      uint2 v;
      if (t > 0) {
        v = spin_load8(out + (size_t)(t - 1) * HID + 4 * tid);
      } else {
        v.x = 0u; v.y = 0u;
      }
      ((uint2*)hbuf[p])[tid] = v;
    } else if (t + 2 < TSTEPS) {
      const int i = tid - 256;
      int pw = rx + 2;
      if (pw >= 3) pw -= 3;
      uint2 v;
      if (l == 0) v = *(const uint2*)(in + (size_t)(t + 2) * HID + 4 * i);
      else        v = spin_load8(in + (size_t)(t + 2) * HID + 4 * i);
      ((uint2*)xbuf[pw])[i] = v;
    }
    __syncthreads();   // (c)

    // ---- (3) gh dots from hbuf[p] ----
    {
      const uint4* cp = (const uint4*)hbuf[p];
      float a0 = 0.f, a1 = 0.f, a2 = 0.f, a3 = 0.f;
#pragma unroll
      for (int s = 0; s < 4; ++s) {
        uint4 c = cp[kc + 32 * s];
        a0 = fdot2f(wB[0][4 * s + 0], c.x, a0);
        a1 = fdot2f(wB[1][4 * s + 0], c.x, a1);
        a2 = fdot2f(wB[2][4 * s + 0], c.x, a2);
        a3 = fdot2f(wB[3][4 * s + 0], c.x, a3);
        a0 = fdot2f(wB[0][4 * s + 1], c.y, a0);
        a1 = fdot2f(wB[1][4 * s + 1], c.y, a1);
        a2 = fdot2f(wB[2][4 * s + 1], c.y, a2);
        a3 = fdot2f(wB[3][4 * s + 1], c.y, a3);
        a0 = fdot2f(wB[0][4 * s + 2], c.z, a0);
        a1 = fdot2f(wB[1][4 * s + 2], c.z, a1);
        a2 = fdot2f(wB[2][4 * s + 2], c.z, a2);
        a3 = fdot2f(wB[3][4 * s + 2], c.z, a3);
        a0 = fdot2f(wB[0][4 * s + 3], c.w, a0);
        a1 = fdot2f(wB[1][4 * s + 3], c.w, a1);
        a2 = fdot2f(wB[2][4 * s + 3], c.w, a2);
        a3 = fdot2f(wB[3][4 * s + 3], c.w, a3);
      }
      a0 = dpp_red32(a0);
      a1 = dpp_red32(a1);
      a2 = dpp_red32(a2);
      a3 = dpp_red32(a3);
      if ((lane & 31) == 31) {
        float4 s4; s4.x = a0; s4.y = a1; s4.z = a2; s4.w = a3;
        *((float4*)&scr[p][64 + 4 * RG]) = s4;
      }
    }
    __syncthreads();   // (d)

    // ---- (4) gates distributed over waves 0-3 (6 columns each) ----
    if (gate_owner) {
      float ir = scr[p][3 * jjg + 0] + b6[0];
      float iz = scr[p][3 * jjg + 1] + b6[1];
      float in_ = scr[p][3 * jjg + 2] + b6[2];
      float hr = scr[p][64 + 3 * jjg + 0] + b6[3];
      float hz = scr[p][64 + 3 * jjg + 1] + b6[4];
      float hn = scr[p][64 + 3 * jjg + 2] + b6[5];
      float rr = 1.f / (1.f + __expf(-(ir + hr)));
      float zz = 1.f / (1.f + __expf(-(iz + hz)));
      float targ = in_ + rr * hn;
      targ = fminf(fmaxf(targ, -15.f), 15.f);
      float e2 = __expf(2.f * targ);
      float nn = (e2 - 1.f) / (e2 + 1.f);
      float hv = (1.f - zz) * nn + zz * hprev;
      hprev = hv;
      u32 hb = (u32)__half_as_ushort(__float2half_rn(hv));
      const __half* dst = out + (size_t)t * HID + h_base + jjg;
      asm volatile("global_store_short %0, %1, off sc0 sc1" :: "v"(dst), "v"(hb));
    }

    rx += 1;
    if (rx >= 3) rx -= 3;
  }
}

// ---------------------------------------------------------------------------
// lin2: out[o,t,io] = h5[t] . w2[o*32+io] + b2   (h5 = S5, fp16)
// ---------------------------------------------------------------------------
__global__ __launch_bounds__(256) void lin2_kernel(
    const __half* __restrict__ h5, const float* __restrict__ w2,
    const float* __restrict__ b2, float* __restrict__ out) {
  __shared__ float at[64][65];
  __shared__ float bt[64][65];
  const int tid = threadIdx.x;
  const int t0 = blockIdx.x * 64;
  const int j0 = blockIdx.y * 64;
  const int tt0 = (tid & 15) * 4;
  const int jj0 = (tid >> 4) * 4;
  float acc[4][4] = {};
  for (int kc = 0; kc < 1024; kc += 64) {
    __syncthreads();
#pragma unroll
    for (int m = 0; m < 16; ++m) {
      int e = tid + m * 256;
      int tt = e >> 6, kk = e & 63;
      at[tt][kk] = __half2float(h5[(size_t)(t0 + tt) * HID + kc + kk]);
    }
#pragma unroll
    for (int m = 0; m < 16; ++m) {
      int e = tid + m * 256;
      int jj = e >> 6, kk = e & 63;
      bt[jj][kk] = w2[(size_t)(j0 + jj) * HID + kc + kk];
    }
    __syncthreads();
    for (int kk = 0; kk < 64; ++kk) {
      float la[4], wa[4];
#pragma unroll
      for (int i = 0; i < 4; ++i) la[i] = at[tt0 + i][kk];
#pragma unroll
      for (int j = 0; j < 4; ++j) wa[j] = bt[jj0 + j][kk];
#pragma unroll
      for (int i = 0; i < 4; ++i)
#pragma unroll
        for (int j = 0; j < 4; ++j) acc[i][j] = fmaf(la[i], wa[j], acc[i][j]);
    }
  }
#pragma unroll
  for (int i = 0; i < 4; ++i)
#pragma unroll
    for (int jq = 0; jq < 4; ++jq) {
      int j = j0 + jj0 + jq;
      out[(size_t)(j >> 5) * (TSTEPS * 32) + (size_t)(t0 + tt0 + i) * 32 + (j & 31)] =
          acc[i][jq] + b2[j];
    }
}

extern "C" void kernel_launch(void* const* d_in, const int* in_sizes, int n_in,
                              void* d_out, int out_size, void* d_ws, size_t ws_size,
                              hipStream_t stream) {
  const float* x   = (const float*)d_in[0];
  const float* w1  = (const float*)d_in[1];
  const float* b1  = (const float*)d_in[2];
  const float* wih = (const float*)d_in[3];
  const float* whh = (const float*)d_in[4];
  const float* bih = (const float*)d_in[5];
  const float* bhh = (const float*)d_in[6];
  const float* w2  = (const float*)d_in[7];
  const float* b2  = (const float*)d_in[8];
  float* out = (float*)d_out;

  __half* Xh = (__half*)d_ws;  // 6 fp16 slabs S0..S5 of [T][H] (24 MB)

  // arm canaries in S1..S5 (re-armed every launch/replay)
  fill_canary<<<1280, 256, 0, stream>>>((u32*)(Xh + THS),
                                        (long)NDEPTH * (long)THS / 2);
  lin1_kernel<<<dim3(64, 8), 256, 0, stream>>>(x, w1, b1, Xh);
  gru_pipe<<<NBLOCKS, 512, 0, stream>>>(wih, whh, bih, bhh, Xh);
  lin2_kernel<<<dim3(32, 4), 256, 0, stream>>>(Xh + (size_t)NDEPTH * THS,
                                               w2, b2, out);
}